// Round 1
// 658.468 us; speedup vs baseline: 1.3760x; 1.3760x over previous
//
#include <hip/hip_runtime.h>
#include <cfloat>
#include <cstddef>

typedef __attribute__((ext_vector_type(8))) short bf16x8;
typedef __attribute__((ext_vector_type(4))) float f32x4;

#define NKEYS    100000
#define SPLITS   61
#define SPLITLEN 1664
#define NKP      (SPLITS * SPLITLEN)   /* 101504 padded key rows */
#define NCHUNK   (SPLITLEN / 128)      /* 13 chunks of 128 keys */

// ---------------- helpers ----------------------------------------------------
__device__ __forceinline__ unsigned short f2bf(float x) {
    unsigned int u = __float_as_uint(x);
    unsigned int r = (u + 0x7fffu + ((u >> 16) & 1u)) >> 16;
    return (unsigned short)r;
}

__device__ __forceinline__ void async16(void* lds, const void* g) {
    __builtin_amdgcn_global_load_lds(
        (const __attribute__((address_space(1))) unsigned int*)g,
        (__attribute__((address_space(3))) unsigned int*)lds, 16, 0, 0);
}

// monotone float->uint, keep 21 high bits, pack 11-bit local key index
__device__ __forceinline__ unsigned pack_si(float sc, unsigned local) {
    unsigned u = __float_as_uint(sc);
    unsigned m = ((int)u < 0) ? ~u : (u | 0x80000000u);
    return (m & 0xFFFFF800u) | local;
}

__device__ __forceinline__ void ins5u(unsigned (&a)[5], unsigned v) {
    if (v > a[4]) {
        a[4] = v;
        #pragma unroll
        for (int i = 4; i > 0; --i) {
            if (a[i] > a[i - 1]) { unsigned t = a[i]; a[i] = a[i - 1]; a[i - 1] = t; }
        }
    }
}

// ---------------- generic tiled GEMM: C = act(A@W + bias) --------------------
__global__ __launch_bounds__(256) void gemm_bias_act(
    const float* __restrict__ A, const float* __restrict__ W,
    const float* __restrict__ bias, float* __restrict__ C,
    int M, int N, int K, int do_gelu)
{
    __shared__ float sA[16][64];
    __shared__ float sW[16][64];
    const int tid = threadIdx.x;
    const int tx = tid & 15, ty = tid >> 4;
    const int m0 = blockIdx.y * 64, n0 = blockIdx.x * 64;
    const int arow = tid >> 2, akk = (tid & 3) << 2;
    const int wrow = tid >> 4, wcol = (tid & 15) << 2;
    float acc[4][4] = {};
    for (int k0 = 0; k0 < K; k0 += 16) {
        float4 av = *(const float4*)(A + (size_t)(m0 + arow) * K + k0 + akk);
        float4 wv = *(const float4*)(W + (size_t)(k0 + wrow) * N + n0 + wcol);
        __syncthreads();
        sA[akk + 0][arow] = av.x;
        sA[akk + 1][arow] = av.y;
        sA[akk + 2][arow] = av.z;
        sA[akk + 3][arow] = av.w;
        *(float4*)&sW[wrow][wcol] = wv;
        __syncthreads();
        #pragma unroll
        for (int kk = 0; kk < 16; ++kk) {
            float4 a = *(const float4*)&sA[kk][ty << 2];
            float4 w = *(const float4*)&sW[kk][tx << 2];
            float av4[4] = {a.x, a.y, a.z, a.w};
            float wv4[4] = {w.x, w.y, w.z, w.w};
            #pragma unroll
            for (int i = 0; i < 4; ++i)
                #pragma unroll
                for (int j = 0; j < 4; ++j)
                    acc[i][j] = fmaf(av4[i], wv4[j], acc[i][j]);
        }
    }
    float4 bv = *(const float4*)(bias + n0 + (tx << 2));
    float bias4[4] = {bv.x, bv.y, bv.z, bv.w};
    #pragma unroll
    for (int i = 0; i < 4; ++i) {
        float o[4];
        #pragma unroll
        for (int j = 0; j < 4; ++j) {
            float v = acc[i][j] + bias4[j];
            if (do_gelu) v = 0.5f * v * (1.0f + erff(v * 0.70710678118654752f));
            o[j] = v;
        }
        float4 ov = {o[0], o[1], o[2], o[3]};
        *(float4*)(C + (size_t)(m0 + (ty << 2) + i) * N + n0 + (tx << 2)) = ov;
    }
}

// ---------------- row LayerNorm (in-place), C in {256,512} -------------------
__global__ __launch_bounds__(256) void ln_rows(
    float* __restrict__ X, const float* __restrict__ g, const float* __restrict__ b, int C)
{
    const int row = blockIdx.x;
    const int tid = threadIdx.x;
    float* xr = X + (size_t)row * C;
    float v0 = xr[tid];
    float v1 = (C > 256) ? xr[tid + 256] : 0.0f;
    float s = v0 + v1;
    float ss = v0 * v0 + v1 * v1;
    #pragma unroll
    for (int off = 32; off > 0; off >>= 1) {
        s  += __shfl_xor(s, off);
        ss += __shfl_xor(ss, off);
    }
    __shared__ float red[10];
    const int wave = tid >> 6, lane = tid & 63;
    if (lane == 0) { red[wave] = s; red[wave + 4] = ss; }
    __syncthreads();
    if (tid == 0) {
        float S  = red[0] + red[1] + red[2] + red[3];
        float SS = red[4] + red[5] + red[6] + red[7];
        float m = S / C;
        float var = SS / C - m * m;
        red[8] = m;
        red[9] = 1.0f / sqrtf(var + 1e-5f);
    }
    __syncthreads();
    float m = red[8], inv = red[9];
    xr[tid] = (v0 - m) * inv * g[tid] + b[tid];
    if (C > 256) xr[tid + 256] = (v1 - m) * inv * g[tid + 256] + b[tid + 256];
}

// ---------------- fp32 rows -> bf16 rows + squared norms (256-wide rows) -----
__global__ __launch_bounds__(256) void prep_rows(
    const float* __restrict__ X, unsigned short* __restrict__ xh,
    float* __restrict__ x2, int nvalid, int ntot)
{
    const int row = blockIdx.x * 4 + (threadIdx.x >> 6);
    const int lane = threadIdx.x & 63;
    if (row >= ntot) return;
    if (row < nvalid) {
        float4 v = *(const float4*)(X + (size_t)row * 256 + (lane << 2));
        float ss = v.x * v.x + v.y * v.y + v.z * v.z + v.w * v.w;
        #pragma unroll
        for (int off = 32; off > 0; off >>= 1) ss += __shfl_xor(ss, off);
        ushort4 h;
        h.x = f2bf(v.x); h.y = f2bf(v.y); h.z = f2bf(v.z); h.w = f2bf(v.w);
        *(ushort4*)(xh + (size_t)row * 256 + (lane << 2)) = h;
        if (lane == 0) x2[row] = ss;
    } else {
        ushort4 z = {0, 0, 0, 0};
        *(ushort4*)(xh + (size_t)row * 256 + (lane << 2)) = z;
        if (lane == 0) x2[row] = 0.0f;
    }
}

// ---------------- MFMA distance + fused per-split top-5 ----------------------
// Block = 128 queries (4 waves x 32) x one key split. Per wave: 2 A-tiles so
// each B ds_read_b128 feeds 2 MFMAs. Double-buffered LDS staging with
// issue-early global_load_lds: ONE barrier per 64-dim K-step (T3 2-phase).
// Bijective XCD swizzle co-locates a split's 8 query-blocks on one XCD so the
// 852 KB key slice is L2-resident. Top-5 kept as packed (score|idx) uints.
__global__ __launch_bounds__(256, 2) void dist_topk_mfma(
    const unsigned short* __restrict__ khi, const unsigned short* __restrict__ qhi,
    const float* __restrict__ k2, unsigned* __restrict__ cand_p)
{
    __shared__ unsigned short sB[2][8192];   // 2 x 16 KB double buffer
    const int tid = threadIdx.x;
    const int lane = tid & 63;
    const int wv = tid >> 6;

    // bijective swizzle: fid -> (split, jq); split s<56 has all 8 blocks with
    // fid % 8 == s/7 (same XCD under round-robin dispatch); splits 56..60 spread.
    const int fid = blockIdx.x;
    const int rr = fid & 7, row = fid >> 3;            // row in 0..60
    int split, jq;
    if (row < 56) { split = rr * 7 + (row >> 3); jq = row & 7; }
    else { int slot = ((row - 56) << 3) + rr; split = 56 + (slot >> 3); jq = slot & 7; }
    const int kstart = split * SPLITLEN;
    const int q0 = jq * 128 + wv * 32;

    // A fragments: 2 tiles x 16 queries x full K=256 (8 steps of 32), in regs
    bf16x8 aF[2][8];
    #pragma unroll
    for (int qt = 0; qt < 2; ++qt) {
        const unsigned short* qb = qhi
            + (((size_t)(q0 + qt * 16 + (lane & 15))) << 8) + ((lane >> 4) << 3);
        #pragma unroll
        for (int s = 0; s < 8; ++s) aF[qt][s] = *(const bf16x8*)(qb + s * 32);
    }

    // per-thread staging bases (4 x 16B per 64-dim step), frag-ordered LDS
    size_t soff[4];
    int ldst[4];
    #pragma unroll
    for (int i = 0; i < 4; ++i) {
        int e = i * 256 + tid;
        int h = e >> 9, t = (e >> 6) & 7, L = e & 63;
        soff[i] = (((size_t)(kstart + t * 16 + (L & 15))) << 8)
                + (h << 5) + ((L >> 4) << 3);
        ldst[i] = e << 3;
    }

    unsigned bp[2][4][5];
    #pragma unroll
    for (int qt = 0; qt < 2; ++qt)
        #pragma unroll
        for (int r = 0; r < 4; ++r)
            #pragma unroll
            for (int j = 0; j < 5; ++j) bp[qt][r][j] = 0u;

    // prologue: stage step 0 into buffer 0
    #pragma unroll
    for (int i = 0; i < 4; ++i)
        async16(&sB[0][ldst[i]], khi + soff[i]);

    int cur = 0;
    for (int c = 0; c < NCHUNK; ++c) {
        const int coff = c << 15;               // c * 128 keys * 256 dims (shorts)
        f32x4 acc[2][8];
        #pragma unroll
        for (int qt = 0; qt < 2; ++qt)
            #pragma unroll
            for (int t = 0; t < 8; ++t) acc[qt][t] = (f32x4){0.f, 0.f, 0.f, 0.f};

        #pragma unroll
        for (int st = 0; st < 4; ++st) {
            __syncthreads();                    // buf[cur] staged (vmcnt drained)
            // issue next step's staging into buf[cur^1] (overlaps MFMA below)
            const int g = (c << 2) + st;
            if (g + 1 < NCHUNK * 4) {
                const int ns = (st + 1) & 3;
                const int ncoff = (st == 3) ? (coff + 32768) : coff;
                #pragma unroll
                for (int i = 0; i < 4; ++i)
                    async16(&sB[cur ^ 1][ldst[i]],
                            khi + soff[i] + (size_t)(ncoff + (ns << 6)));
            }
            // compute current step: 16 ds_read_b128 -> 32 MFMAs
            #pragma unroll
            for (int h = 0; h < 2; ++h) {
                #pragma unroll
                for (int t = 0; t < 8; ++t) {
                    bf16x8 b = *(const bf16x8*)
                        &sB[cur][((((h << 3) + t) << 6) | lane) << 3];
                    acc[0][t] = __builtin_amdgcn_mfma_f32_16x16x32_bf16(
                        aF[0][(st << 1) + h], b, acc[0][t], 0, 0, 0);
                    acc[1][t] = __builtin_amdgcn_mfma_f32_16x16x32_bf16(
                        aF[1][(st << 1) + h], b, acc[1][t], 0, 0, 0);
                }
            }
            cur ^= 1;
        }

        // fused epilogue: scores + running per-lane top-5 (8 query rows/lane)
        const int kb = c << 7;
        #pragma unroll
        for (int t = 0; t < 8; ++t) {
            const unsigned local = (unsigned)(kb + t * 16 + (lane & 15));
            const int key = kstart + (int)local;
            const float k2v = k2[key];
            const bool valid = key < NKEYS;
            #pragma unroll
            for (int qt = 0; qt < 2; ++qt)
                #pragma unroll
                for (int r = 0; r < 4; ++r) {
                    float sc = fmaf(-0.5f, k2v, acc[qt][t][r]);
                    unsigned p = valid ? pack_si(sc, local) : 0u;
                    ins5u(bp[qt][r], p);
                }
        }
    }

    // butterfly merge across the 16 lanes of each quad (same 8 query rows)
    #pragma unroll
    for (int m = 1; m <= 8; m <<= 1) {
        #pragma unroll
        for (int qt = 0; qt < 2; ++qt)
            #pragma unroll
            for (int r = 0; r < 4; ++r) {
                unsigned o[5];
                #pragma unroll
                for (int j = 0; j < 5; ++j)
                    o[j] = (unsigned)__shfl_xor((int)bp[qt][r][j], m);
                #pragma unroll
                for (int j = 0; j < 5; ++j) ins5u(bp[qt][r], o[j]);
            }
    }
    if ((lane & 15) == 0) {
        #pragma unroll
        for (int qt = 0; qt < 2; ++qt)
            #pragma unroll
            for (int r = 0; r < 4; ++r) {
                const int q = q0 + qt * 16 + ((lane >> 4) << 2) + r;
                #pragma unroll
                for (int j = 0; j < 5; ++j)
                    cand_p[(size_t)(split * 5 + j) * 1024 + q] = bp[qt][r][j];
            }
    }
}

// ---------------- merge per-split candidates -> approx top-8 per query -------
// cand_p transposed [split*5][1024]: coalesced reads; packed uints compare
// monotonically with quantized score; early-break on the sorted 5-run.
__global__ __launch_bounds__(256) void merge8(
    const unsigned* __restrict__ cand_p, int* __restrict__ idx8)
{
    const int q = blockIdx.x * 256 + threadIdx.x;
    unsigned fp[8]; int fi[8];
    #pragma unroll
    for (int j = 0; j < 8; ++j) { fp[j] = 0u; fi[j] = 0; }
    for (int sp = 0; sp < SPLITS; ++sp) {
        for (int j = 0; j < 5; ++j) {
            unsigned v = cand_p[(size_t)(sp * 5 + j) * 1024 + q];
            if (v <= fp[7]) break;              // run is sorted descending
            fp[7] = v; fi[7] = sp * SPLITLEN + (int)(v & 2047u);
            #pragma unroll
            for (int i = 7; i > 0; --i) {
                if (fp[i] > fp[i - 1]) {
                    unsigned tv = fp[i]; fp[i] = fp[i - 1]; fp[i - 1] = tv;
                    int ti = fi[i]; fi[i] = fi[i - 1]; fi[i - 1] = ti;
                }
            }
        }
    }
    #pragma unroll
    for (int j = 0; j < 8; ++j) idx8[q * 8 + j] = fi[j];
}

// ---------------- exact fp32 rerank of top-8 -> top-5, weights, confidence ---
__global__ __launch_bounds__(256) void rerank(
    const float* __restrict__ qc, const float* __restrict__ keys,
    const float* __restrict__ k2, const float* __restrict__ q2,
    const int* __restrict__ idx8, float* __restrict__ w5,
    int* __restrict__ idx5, float* __restrict__ conf)
{
    const int q = blockIdx.x * 4 + (threadIdx.x >> 6);
    const int lane = threadIdx.x & 63;
    float4 qv = *(const float4*)(qc + (size_t)q * 256 + (lane << 2));
    float dot[8]; int cidx[8];
    #pragma unroll
    for (int c = 0; c < 8; ++c) {
        cidx[c] = idx8[q * 8 + c];
        float4 kv = *(const float4*)(keys + (size_t)cidx[c] * 256 + (lane << 2));
        dot[c] = qv.x * kv.x + qv.y * kv.y + qv.z * kv.z + qv.w * kv.w;
    }
    #pragma unroll
    for (int c = 0; c < 8; ++c)
        #pragma unroll
        for (int off = 32; off > 0; off >>= 1) dot[c] += __shfl_xor(dot[c], off);
    if (lane == 0) {
        float d[8]; int di[8];
        const float qq = q2[q];
        #pragma unroll
        for (int c = 0; c < 8; ++c) {
            d[c] = fmaxf(qq + k2[cidx[c]] - 2.0f * dot[c], 0.0f);
            di[c] = cidx[c];
        }
        #pragma unroll
        for (int a = 1; a < 8; ++a) {           // insertion sort ascending
            float dv = d[a]; int iv = di[a]; int b = a;
            while (b > 0 && d[b - 1] > dv) { d[b] = d[b - 1]; di[b] = di[b - 1]; --b; }
            d[b] = dv; di[b] = iv;
        }
        float w[5], sum = 0.0f;
        #pragma unroll
        for (int j = 0; j < 5; ++j) { w[j] = 1.0f / (d[j] + 1e-6f); sum += w[j]; }
        #pragma unroll
        for (int j = 0; j < 5; ++j) { w5[q * 5 + j] = w[j] / sum; idx5[q * 5 + j] = di[j]; }
        conf[q] = 1.0f / (d[0] + 1e-6f);
    }
}

// ---------------- gather values_c rows for decompress ------------------------
__global__ __launch_bounds__(256) void gather_rows(
    const float* __restrict__ values, const int* __restrict__ idx5, float* __restrict__ X0)
{
    const int row = blockIdx.x;
    const int idx = idx5[row];
    X0[(size_t)row * 256 + threadIdx.x] = values[(size_t)idx * 256 + threadIdx.x];
}

// ---------------- weighted combine of 5 decompressed h2 rows -----------------
__global__ __launch_bounds__(128) void combine_weighted(
    const float* __restrict__ h2d, const float* __restrict__ w5, float* __restrict__ z)
{
    const int q = blockIdx.x;
    const int t = threadIdx.x;
    float4 acc = {0.0f, 0.0f, 0.0f, 0.0f};
    #pragma unroll
    for (int i = 0; i < 5; ++i) {
        float w = w5[q * 5 + i];
        float4 v = *(const float4*)(h2d + ((size_t)q * 5 + i) * 512 + (t << 2));
        acc.x = fmaf(w, v.x, acc.x);
        acc.y = fmaf(w, v.y, acc.y);
        acc.z = fmaf(w, v.z, acc.z);
        acc.w = fmaf(w, v.w, acc.w);
    }
    *(float4*)(z + (size_t)q * 512 + (t << 2)) = acc;
}

// ---------------- workspace layout (float offsets), ~83 MB -------------------
#define OFF_KHI 0               /* NKP x 256 bf16 = 12992512 floats */
#define OFF_K2  12992512
#define OFF_QHI 13094016
#define OFF_Q2  13225088
#define OFF_CS  13226112        /* cand_p: 305 x 1024 uints (fits 1024x305) */
#define OFF_CI  13538432        /* unused now */
#define OFF_I8  13850752
#define OFF_H1  13858944
#define OFF_H2  14383232
#define OFF_QC  14645376
#define OFF_X0  14907520
#define OFF_T1  16218240
#define OFF_T2  17528960
#define OFF_Z   20150400
#define OFF_W5  20674688
#define OFF_I5  20679808

extern "C" void kernel_launch(void* const* d_in, const int* in_sizes, int n_in,
                              void* d_out, int out_size, void* d_ws, size_t ws_size,
                              hipStream_t stream) {
    const float* query  = (const float*)d_in[0];
    const float* keys   = (const float*)d_in[1];
    const float* values = (const float*)d_in[2];
    const float* cW1 = (const float*)d_in[3];  const float* cb1 = (const float*)d_in[4];
    const float* cg1 = (const float*)d_in[5];  const float* cB1 = (const float*)d_in[6];
    const float* cW2 = (const float*)d_in[7];  const float* cb2 = (const float*)d_in[8];
    const float* cg2 = (const float*)d_in[9];  const float* cB2 = (const float*)d_in[10];
    const float* cW3 = (const float*)d_in[11]; const float* cb3 = (const float*)d_in[12];
    const float* dW1 = (const float*)d_in[13]; const float* db1 = (const float*)d_in[14];
    const float* dg1 = (const float*)d_in[15]; const float* dB1 = (const float*)d_in[16];
    const float* dW2 = (const float*)d_in[17]; const float* db2 = (const float*)d_in[18];
    const float* dg2 = (const float*)d_in[19]; const float* dB2 = (const float*)d_in[20];
    const float* dW3 = (const float*)d_in[21]; const float* db3 = (const float*)d_in[22];
    float* out = (float*)d_out;
    float* ws  = (float*)d_ws;

    unsigned short* khi = (unsigned short*)(ws + OFF_KHI);
    float* k2 = ws + OFF_K2;
    unsigned short* qhi = (unsigned short*)(ws + OFF_QHI);
    float* q2 = ws + OFF_Q2;
    unsigned* cand_p = (unsigned*)(ws + OFF_CS);
    int* idx8 = (int*)(ws + OFF_I8);
    float* h1 = ws + OFF_H1;  float* h2 = ws + OFF_H2;  float* qc = ws + OFF_QC;
    float* X0 = ws + OFF_X0;  float* t1 = ws + OFF_T1;  float* t2 = ws + OFF_T2;
    float* z  = ws + OFF_Z;
    float* w5 = ws + OFF_W5;  int* idx5 = (int*)(ws + OFF_I5);

    // keys -> bf16 + exact k2 (pad rows zeroed)
    prep_rows<<<NKP / 4, 256, 0, stream>>>(keys, khi, k2, NKEYS, NKP);

    // compress: q_c = MLP(query)
    gemm_bias_act<<<dim3(8, 16),  256, 0, stream>>>(query, cW1, cb1, h1, 1024, 512, 1024, 1);
    ln_rows<<<1024, 256, 0, stream>>>(h1, cg1, cB1, 512);
    gemm_bias_act<<<dim3(4, 16),  256, 0, stream>>>(h1, cW2, cb2, h2, 1024, 256, 512, 1);
    ln_rows<<<1024, 256, 0, stream>>>(h2, cg2, cB2, 256);
    gemm_bias_act<<<dim3(4, 16),  256, 0, stream>>>(h2, cW3, cb3, qc, 1024, 256, 256, 0);
    prep_rows<<<256, 256, 0, stream>>>(qc, qhi, q2, 1024, 1024);

    // approx distances via MFMA + fused top-5, then exact rerank of top-8
    dist_topk_mfma<<<SPLITS * 8, 256, 0, stream>>>(khi, qhi, k2, cand_p);
    merge8<<<4, 256, 0, stream>>>(cand_p, idx8);
    rerank<<<256, 256, 0, stream>>>(qc, keys, k2, q2, idx8, w5, idx5, out + 1024 * 1024);

    // decompress 5120 gathered rows, combine, final linear into d_out
    gather_rows<<<5120, 256, 0, stream>>>(values, idx5, X0);
    gemm_bias_act<<<dim3(4, 80),  256, 0, stream>>>(X0, dW1, db1, t1, 5120, 256, 256, 1);
    ln_rows<<<5120, 256, 0, stream>>>(t1, dg1, dB1, 256);
    gemm_bias_act<<<dim3(8, 80),  256, 0, stream>>>(t1, dW2, db2, t2, 5120, 512, 256, 1);
    ln_rows<<<5120, 256, 0, stream>>>(t2, dg2, dB2, 512);
    combine_weighted<<<1024, 128, 0, stream>>>(t2, w5, z);
    gemm_bias_act<<<dim3(16, 16), 256, 0, stream>>>(z, dW3, db3, out, 1024, 1024, 512, 0);
}

// Round 3
// 557.005 us; speedup vs baseline: 1.6266x; 1.1822x over previous
//
#include <hip/hip_runtime.h>
#include <cfloat>
#include <cstddef>

typedef __attribute__((ext_vector_type(8))) short bf16x8;
typedef __attribute__((ext_vector_type(4))) float f32x4;

#define NKEYS    100000
#define SPLITS   61
#define SPLITLEN 1664
#define NKP      (SPLITS * SPLITLEN)   /* 101504 padded key rows */
#define NCHUNK   (SPLITLEN / 128)      /* 13 chunks of 128 keys */

// ---------------- helpers ----------------------------------------------------
__device__ __forceinline__ unsigned short f2bf(float x) {
    unsigned int u = __float_as_uint(x);
    unsigned int r = (u + 0x7fffu + ((u >> 16) & 1u)) >> 16;
    return (unsigned short)r;
}
__device__ __forceinline__ float bf2f(unsigned short h) {
    return __uint_as_float((unsigned)h << 16);
}
// fp32 -> bf16 hi + bf16 lo (x ~= hi + lo to ~2^-17 rel)
__device__ __forceinline__ void split2(float x, unsigned short& h, unsigned short& l) {
    h = f2bf(x);
    float r = x - bf2f(h);
    l = f2bf(r);
}

__device__ __forceinline__ void async16(void* lds, const void* g) {
    __builtin_amdgcn_global_load_lds(
        (const __attribute__((address_space(1))) unsigned int*)g,
        (__attribute__((address_space(3))) unsigned int*)lds, 16, 0, 0);
}

// monotone float->uint, keep 21 high bits, pack 11-bit local key index
__device__ __forceinline__ unsigned pack_si(float sc, unsigned local) {
    unsigned u = __float_as_uint(sc);
    unsigned m = ((int)u < 0) ? ~u : (u | 0x80000000u);
    return (m & 0xFFFFF800u) | local;
}

__device__ __forceinline__ void ins5u(unsigned (&a)[5], unsigned v) {
    if (v > a[4]) {
        a[4] = v;
        #pragma unroll
        for (int i = 4; i > 0; --i) {
            if (a[i] > a[i - 1]) { unsigned t = a[i]; a[i] = a[i - 1]; a[i - 1] = t; }
        }
    }
}

// ---------------- split-bf16 MFMA GEMM: C = act(A@W + bias) ------------------
// A given as hi/lo bf16 [M][K]; W given transposed+split hi/lo bf16 [N][K].
// acc = Ahi*Whi + Ahi*Wlo + Alo*Whi (3 MFMA passes, ~2^-17 rel error).
// Block: 64x64 tile, 4 waves (2x2), each wave 32x32 = 2x2 16x16 frags.
// Frag-ordered global_load_lds staging, double buffer, 1 barrier / K32-step.
__global__ __launch_bounds__(256, 2) void mfma_gemm(
    const unsigned short* __restrict__ Ahi, const unsigned short* __restrict__ Alo,
    const unsigned short* __restrict__ Whi, const unsigned short* __restrict__ Wlo,
    const float* __restrict__ bias, float* __restrict__ C,
    int M, int N, int K, int do_gelu)
{
    __shared__ unsigned short sT[2][8192];   // 2 x 16 KB (4 arrays x 4 tiles x 1KB)
    const int tid = threadIdx.x;
    const int lane = tid & 63;
    const int wv = tid >> 6;
    const int wr = wv >> 1, wc = wv & 1;
    const int m0 = blockIdx.y << 6, n0 = blockIdx.x << 6;

    // staging: load i stages array i (Ahi,Alo,Whi,Wlo), tile = wv, per-lane row
    const int rl = lane & 15, kq = (lane >> 4) << 3;
    const unsigned short* sp[4];
    sp[0] = Ahi + (size_t)(m0 + (wv << 4) + rl) * K + kq;
    sp[1] = Alo + (size_t)(m0 + (wv << 4) + rl) * K + kq;
    sp[2] = Whi + (size_t)(n0 + (wv << 4) + rl) * K + kq;
    sp[3] = Wlo + (size_t)(n0 + (wv << 4) + rl) * K + kq;
    const int ldss = (wv << 9) | (lane << 3);   // short index within 2048-short arr

    f32x4 acc[2][2];
    #pragma unroll
    for (int p = 0; p < 2; ++p)
        #pragma unroll
        for (int q = 0; q < 2; ++q) acc[p][q] = (f32x4){0.f, 0.f, 0.f, 0.f};

    const int steps = K >> 5;
    // prologue: stage step 0 into buf 0
    #pragma unroll
    for (int i = 0; i < 4; ++i)
        async16(&sT[0][(i << 11) + ldss], sp[i]);

    for (int s = 0; s < steps; ++s) {
        const int cur = s & 1;
        __syncthreads();                       // buf[cur] staged (vmcnt drained)
        if (s + 1 < steps) {
            const int ko = (s + 1) << 5;
            #pragma unroll
            for (int i = 0; i < 4; ++i)
                async16(&sT[cur ^ 1][(i << 11) + ldss], sp[i] + ko);
        }
        bf16x8 ah[2], al[2], wh[2], wl[2];
        #pragma unroll
        for (int p = 0; p < 2; ++p) {
            ah[p] = *(const bf16x8*)&sT[cur][(((wr << 1) + p) << 9) | (lane << 3)];
            al[p] = *(const bf16x8*)&sT[cur][2048 + ((((wr << 1) + p) << 9) | (lane << 3))];
        }
        #pragma unroll
        for (int q = 0; q < 2; ++q) {
            wh[q] = *(const bf16x8*)&sT[cur][4096 + ((((wc << 1) + q) << 9) | (lane << 3))];
            wl[q] = *(const bf16x8*)&sT[cur][6144 + ((((wc << 1) + q) << 9) | (lane << 3))];
        }
        #pragma unroll
        for (int p = 0; p < 2; ++p)
            #pragma unroll
            for (int q = 0; q < 2; ++q) {
                acc[p][q] = __builtin_amdgcn_mfma_f32_16x16x32_bf16(ah[p], wh[q], acc[p][q], 0, 0, 0);
                acc[p][q] = __builtin_amdgcn_mfma_f32_16x16x32_bf16(ah[p], wl[q], acc[p][q], 0, 0, 0);
                acc[p][q] = __builtin_amdgcn_mfma_f32_16x16x32_bf16(al[p], wh[q], acc[p][q], 0, 0, 0);
            }
    }

    // epilogue: D frag layout col = lane&15 (n), row = (lane>>4)*4 + j (m)
    #pragma unroll
    for (int q = 0; q < 2; ++q) {
        const int n = n0 + (((wc << 1) + q) << 4) + (lane & 15);
        const float bn = bias[n];
        #pragma unroll
        for (int p = 0; p < 2; ++p) {
            #pragma unroll
            for (int j = 0; j < 4; ++j) {
                const int m = m0 + (((wr << 1) + p) << 4) + ((lane >> 4) << 2) + j;
                float v = acc[p][q][j] + bn;
                if (do_gelu) v = 0.5f * v * (1.0f + erff(v * 0.70710678118654752f));
                C[(size_t)m * N + n] = v;
            }
        }
    }
}

// ---------------- weight transpose + split: W[K][N] -> Thi/Tlo[N][K] ---------
__global__ __launch_bounds__(256) void wsplit(
    const float* __restrict__ W, unsigned short* __restrict__ Thi,
    unsigned short* __restrict__ Tlo, int K, int N)
{
    __shared__ float tile[64][65];
    const int tid = threadIdx.x;
    const int n0 = blockIdx.x << 6, k0 = blockIdx.y << 6;
    const int nl = tid & 63, kg = tid >> 6;
    #pragma unroll
    for (int r = 0; r < 16; ++r)
        tile[kg + (r << 2)][nl] = W[(size_t)(k0 + kg + (r << 2)) * N + n0 + nl];
    __syncthreads();
    const int nn = tid >> 2, kc = (tid & 3) << 4;
    unsigned short* ph = Thi + (size_t)(n0 + nn) * K + k0 + kc;
    unsigned short* pl = Tlo + (size_t)(n0 + nn) * K + k0 + kc;
    #pragma unroll
    for (int c = 0; c < 16; c += 4) {
        ushort4 H, L;
        split2(tile[kc + c + 0][nn], H.x, L.x);
        split2(tile[kc + c + 1][nn], H.y, L.y);
        split2(tile[kc + c + 2][nn], H.z, L.z);
        split2(tile[kc + c + 3][nn], H.w, L.w);
        *(ushort4*)(ph + c) = H;
        *(ushort4*)(pl + c) = L;
    }
}

// ---------------- elementwise fp32 -> bf16 hi/lo (size multiple of 1024) -----
__global__ __launch_bounds__(256) void csplit(
    const float* __restrict__ X, unsigned short* __restrict__ hi,
    unsigned short* __restrict__ lo)
{
    const size_t i = ((size_t)blockIdx.x * 256 + threadIdx.x) << 2;
    float4 v = *(const float4*)(X + i);
    ushort4 H, L;
    split2(v.x, H.x, L.x);
    split2(v.y, H.y, L.y);
    split2(v.z, H.z, L.z);
    split2(v.w, H.w, L.w);
    *(ushort4*)(hi + i) = H;
    *(ushort4*)(lo + i) = L;
}

// ---------------- row LayerNorm (in-place fp32), C in {256,512} --------------
__global__ __launch_bounds__(256) void ln_rows(
    float* __restrict__ X, const float* __restrict__ g, const float* __restrict__ b, int C)
{
    const int row = blockIdx.x;
    const int tid = threadIdx.x;
    float* xr = X + (size_t)row * C;
    float v0 = xr[tid];
    float v1 = (C > 256) ? xr[tid + 256] : 0.0f;
    float s = v0 + v1;
    float ss = v0 * v0 + v1 * v1;
    #pragma unroll
    for (int off = 32; off > 0; off >>= 1) {
        s  += __shfl_xor(s, off);
        ss += __shfl_xor(ss, off);
    }
    __shared__ float red[10];
    const int wave = tid >> 6, lane = tid & 63;
    if (lane == 0) { red[wave] = s; red[wave + 4] = ss; }
    __syncthreads();
    if (tid == 0) {
        float S  = red[0] + red[1] + red[2] + red[3];
        float SS = red[4] + red[5] + red[6] + red[7];
        float m = S / C;
        float var = SS / C - m * m;
        red[8] = m;
        red[9] = 1.0f / sqrtf(var + 1e-5f);
    }
    __syncthreads();
    float m = red[8], inv = red[9];
    xr[tid] = (v0 - m) * inv * g[tid] + b[tid];
    if (C > 256) xr[tid + 256] = (v1 - m) * inv * g[tid + 256] + b[tid + 256];
}

// ---------------- row LayerNorm -> bf16 hi/lo outputs ------------------------
__global__ __launch_bounds__(256) void ln_split(
    const float* __restrict__ X, const float* __restrict__ g, const float* __restrict__ b,
    int C, unsigned short* __restrict__ hi, unsigned short* __restrict__ lo)
{
    const int row = blockIdx.x;
    const int tid = threadIdx.x;
    const float* xr = X + (size_t)row * C;
    float v0 = xr[tid];
    float v1 = (C > 256) ? xr[tid + 256] : 0.0f;
    float s = v0 + v1;
    float ss = v0 * v0 + v1 * v1;
    #pragma unroll
    for (int off = 32; off > 0; off >>= 1) {
        s  += __shfl_xor(s, off);
        ss += __shfl_xor(ss, off);
    }
    __shared__ float red[10];
    const int wave = tid >> 6, lane = tid & 63;
    if (lane == 0) { red[wave] = s; red[wave + 4] = ss; }
    __syncthreads();
    if (tid == 0) {
        float S  = red[0] + red[1] + red[2] + red[3];
        float SS = red[4] + red[5] + red[6] + red[7];
        float m = S / C;
        float var = SS / C - m * m;
        red[8] = m;
        red[9] = 1.0f / sqrtf(var + 1e-5f);
    }
    __syncthreads();
    float m = red[8], inv = red[9];
    {
        float y = (v0 - m) * inv * g[tid] + b[tid];
        unsigned short h, l; split2(y, h, l);
        hi[(size_t)row * C + tid] = h;
        lo[(size_t)row * C + tid] = l;
    }
    if (C > 256) {
        float y = (v1 - m) * inv * g[tid + 256] + b[tid + 256];
        unsigned short h, l; split2(y, h, l);
        hi[(size_t)row * C + tid + 256] = h;
        lo[(size_t)row * C + tid + 256] = l;
    }
}

// ---------------- fp32 rows -> bf16 rows + squared norms (256-wide rows) -----
__global__ __launch_bounds__(256) void prep_rows(
    const float* __restrict__ X, unsigned short* __restrict__ xh,
    float* __restrict__ x2, int nvalid, int ntot)
{
    const int row = blockIdx.x * 4 + (threadIdx.x >> 6);
    const int lane = threadIdx.x & 63;
    if (row >= ntot) return;
    if (row < nvalid) {
        float4 v = *(const float4*)(X + (size_t)row * 256 + (lane << 2));
        float ss = v.x * v.x + v.y * v.y + v.z * v.z + v.w * v.w;
        #pragma unroll
        for (int off = 32; off > 0; off >>= 1) ss += __shfl_xor(ss, off);
        ushort4 h;
        h.x = f2bf(v.x); h.y = f2bf(v.y); h.z = f2bf(v.z); h.w = f2bf(v.w);
        *(ushort4*)(xh + (size_t)row * 256 + (lane << 2)) = h;
        if (lane == 0) x2[row] = ss;
    } else {
        ushort4 z = {0, 0, 0, 0};
        *(ushort4*)(xh + (size_t)row * 256 + (lane << 2)) = z;
        if (lane == 0) x2[row] = 0.0f;
    }
}

// ---------------- MFMA distance + fused per-split top-5 ----------------------
__global__ __launch_bounds__(256, 2) void dist_topk_mfma(
    const unsigned short* __restrict__ khi, const unsigned short* __restrict__ qhi,
    const float* __restrict__ k2, unsigned* __restrict__ cand_p)
{
    __shared__ unsigned short sB[2][8192];   // 2 x 16 KB double buffer
    const int tid = threadIdx.x;
    const int lane = tid & 63;
    const int wv = tid >> 6;

    const int fid = blockIdx.x;
    const int rr = fid & 7, row = fid >> 3;            // row in 0..60
    int split, jq;
    if (row < 56) { split = rr * 7 + (row >> 3); jq = row & 7; }
    else { int slot = ((row - 56) << 3) + rr; split = 56 + (slot >> 3); jq = slot & 7; }
    const int kstart = split * SPLITLEN;
    const int q0 = jq * 128 + wv * 32;

    bf16x8 aF[2][8];
    #pragma unroll
    for (int qt = 0; qt < 2; ++qt) {
        const unsigned short* qb = qhi
            + (((size_t)(q0 + qt * 16 + (lane & 15))) << 8) + ((lane >> 4) << 3);
        #pragma unroll
        for (int s = 0; s < 8; ++s) aF[qt][s] = *(const bf16x8*)(qb + s * 32);
    }

    size_t soff[4];
    int ldst[4];
    #pragma unroll
    for (int i = 0; i < 4; ++i) {
        int e = i * 256 + tid;
        int h = e >> 9, t = (e >> 6) & 7, L = e & 63;
        soff[i] = (((size_t)(kstart + t * 16 + (L & 15))) << 8)
                + (h << 5) + ((L >> 4) << 3);
        ldst[i] = e << 3;
    }

    unsigned bp[2][4][5];
    #pragma unroll
    for (int qt = 0; qt < 2; ++qt)
        #pragma unroll
        for (int r = 0; r < 4; ++r)
            #pragma unroll
            for (int j = 0; j < 5; ++j) bp[qt][r][j] = 0u;

    #pragma unroll
    for (int i = 0; i < 4; ++i)
        async16(&sB[0][ldst[i]], khi + soff[i]);

    int cur = 0;
    for (int c = 0; c < NCHUNK; ++c) {
        const int coff = c << 15;
        f32x4 acc[2][8];
        #pragma unroll
        for (int qt = 0; qt < 2; ++qt)
            #pragma unroll
            for (int t = 0; t < 8; ++t) acc[qt][t] = (f32x4){0.f, 0.f, 0.f, 0.f};

        #pragma unroll
        for (int st = 0; st < 4; ++st) {
            __syncthreads();
            const int g = (c << 2) + st;
            if (g + 1 < NCHUNK * 4) {
                const int ns = (st + 1) & 3;
                const int ncoff = (st == 3) ? (coff + 32768) : coff;
                #pragma unroll
                for (int i = 0; i < 4; ++i)
                    async16(&sB[cur ^ 1][ldst[i]],
                            khi + soff[i] + (size_t)(ncoff + (ns << 6)));
            }
            #pragma unroll
            for (int h = 0; h < 2; ++h) {
                #pragma unroll
                for (int t = 0; t < 8; ++t) {
                    bf16x8 b = *(const bf16x8*)
                        &sB[cur][((((h << 3) + t) << 6) | lane) << 3];
                    acc[0][t] = __builtin_amdgcn_mfma_f32_16x16x32_bf16(
                        aF[0][(st << 1) + h], b, acc[0][t], 0, 0, 0);
                    acc[1][t] = __builtin_amdgcn_mfma_f32_16x16x32_bf16(
                        aF[1][(st << 1) + h], b, acc[1][t], 0, 0, 0);
                }
            }
            cur ^= 1;
        }

        const int kb = c << 7;
        #pragma unroll
        for (int t = 0; t < 8; ++t) {
            const unsigned local = (unsigned)(kb + t * 16 + (lane & 15));
            const int key = kstart + (int)local;
            const float k2v = k2[key];
            const bool valid = key < NKEYS;
            #pragma unroll
            for (int qt = 0; qt < 2; ++qt)
                #pragma unroll
                for (int r = 0; r < 4; ++r) {
                    float sc = fmaf(-0.5f, k2v, acc[qt][t][r]);
                    unsigned p = valid ? pack_si(sc, local) : 0u;
                    ins5u(bp[qt][r], p);
                }
        }
    }

    #pragma unroll
    for (int m = 1; m <= 8; m <<= 1) {
        #pragma unroll
        for (int qt = 0; qt < 2; ++qt)
            #pragma unroll
            for (int r = 0; r < 4; ++r) {
                unsigned o[5];
                #pragma unroll
                for (int j = 0; j < 5; ++j)
                    o[j] = (unsigned)__shfl_xor((int)bp[qt][r][j], m);
                #pragma unroll
                for (int j = 0; j < 5; ++j) ins5u(bp[qt][r], o[j]);
            }
    }
    if ((lane & 15) == 0) {
        #pragma unroll
        for (int qt = 0; qt < 2; ++qt)
            #pragma unroll
            for (int r = 0; r < 4; ++r) {
                const int q = q0 + qt * 16 + ((lane >> 4) << 2) + r;
                #pragma unroll
                for (int j = 0; j < 5; ++j)
                    cand_p[(size_t)(split * 5 + j) * 1024 + q] = bp[qt][r][j];
            }
    }
}

// ---------------- merge per-split candidates -> approx top-8 per query -------
__global__ __launch_bounds__(64) void merge8(
    const unsigned* __restrict__ cand_p, int* __restrict__ idx8)
{
    const int q = blockIdx.x * 64 + threadIdx.x;
    unsigned fp[8]; int fi[8];
    #pragma unroll
    for (int j = 0; j < 8; ++j) { fp[j] = 0u; fi[j] = 0; }
    for (int sp = 0; sp < SPLITS; ++sp) {
        for (int j = 0; j < 5; ++j) {
            unsigned v = cand_p[(size_t)(sp * 5 + j) * 1024 + q];
            if (v <= fp[7]) break;              // run is sorted descending
            fp[7] = v; fi[7] = sp * SPLITLEN + (int)(v & 2047u);
            #pragma unroll
            for (int i = 7; i > 0; --i) {
                if (fp[i] > fp[i - 1]) {
                    unsigned tv = fp[i]; fp[i] = fp[i - 1]; fp[i - 1] = tv;
                    int ti = fi[i]; fi[i] = fi[i - 1]; fi[i - 1] = ti;
                }
            }
        }
    }
    #pragma unroll
    for (int j = 0; j < 8; ++j) idx8[q * 8 + j] = fi[j];
}

// ---------------- exact fp32 rerank of top-8 -> top-5, weights, confidence ---
__global__ __launch_bounds__(256) void rerank(
    const float* __restrict__ qc, const float* __restrict__ keys,
    const float* __restrict__ k2, const float* __restrict__ q2,
    const int* __restrict__ idx8, float* __restrict__ w5,
    int* __restrict__ idx5, float* __restrict__ conf)
{
    const int q = blockIdx.x * 4 + (threadIdx.x >> 6);
    const int lane = threadIdx.x & 63;
    float4 qv = *(const float4*)(qc + (size_t)q * 256 + (lane << 2));
    float dot[8]; int cidx[8];
    #pragma unroll
    for (int c = 0; c < 8; ++c) {
        cidx[c] = idx8[q * 8 + c];
        float4 kv = *(const float4*)(keys + (size_t)cidx[c] * 256 + (lane << 2));
        dot[c] = qv.x * kv.x + qv.y * kv.y + qv.z * kv.z + qv.w * kv.w;
    }
    #pragma unroll
    for (int c = 0; c < 8; ++c)
        #pragma unroll
        for (int off = 32; off > 0; off >>= 1) dot[c] += __shfl_xor(dot[c], off);
    if (lane == 0) {
        float d[8]; int di[8];
        const float qq = q2[q];
        #pragma unroll
        for (int c = 0; c < 8; ++c) {
            d[c] = fmaxf(qq + k2[cidx[c]] - 2.0f * dot[c], 0.0f);
            di[c] = cidx[c];
        }
        #pragma unroll
        for (int a = 1; a < 8; ++a) {
            float dv = d[a]; int iv = di[a]; int b = a;
            while (b > 0 && d[b - 1] > dv) { d[b] = d[b - 1]; di[b] = di[b - 1]; --b; }
            d[b] = dv; di[b] = iv;
        }
        float w[5], sum = 0.0f;
        #pragma unroll
        for (int j = 0; j < 5; ++j) { w[j] = 1.0f / (d[j] + 1e-6f); sum += w[j]; }
        #pragma unroll
        for (int j = 0; j < 5; ++j) { w5[q * 5 + j] = w[j] / sum; idx5[q * 5 + j] = di[j]; }
        conf[q] = 1.0f / (d[0] + 1e-6f);
    }
}

// ---------------- gather values_c rows -> bf16 hi/lo -------------------------
__global__ __launch_bounds__(256) void gather_split(
    const float* __restrict__ values, const int* __restrict__ idx5,
    unsigned short* __restrict__ Xhi, unsigned short* __restrict__ Xlo)
{
    const int row = blockIdx.x;
    const int idx = idx5[row];
    float v = values[(size_t)idx * 256 + threadIdx.x];
    unsigned short h, l; split2(v, h, l);
    Xhi[(size_t)row * 256 + threadIdx.x] = h;
    Xlo[(size_t)row * 256 + threadIdx.x] = l;
}

// ---------------- weighted combine of 5 rows -> bf16 hi/lo z -----------------
__global__ __launch_bounds__(128) void combine_split(
    const float* __restrict__ h2d, const float* __restrict__ w5,
    unsigned short* __restrict__ zhi, unsigned short* __restrict__ zlo)
{
    const int q = blockIdx.x;
    const int t = threadIdx.x;
    float4 acc = {0.0f, 0.0f, 0.0f, 0.0f};
    #pragma unroll
    for (int i = 0; i < 5; ++i) {
        float w = w5[q * 5 + i];
        float4 v = *(const float4*)(h2d + ((size_t)q * 5 + i) * 512 + (t << 2));
        acc.x = fmaf(w, v.x, acc.x);
        acc.y = fmaf(w, v.y, acc.y);
        acc.z = fmaf(w, v.z, acc.z);
        acc.w = fmaf(w, v.w, acc.w);
    }
    ushort4 H, L;
    split2(acc.x, H.x, L.x);
    split2(acc.y, H.y, L.y);
    split2(acc.z, H.z, L.z);
    split2(acc.w, H.w, L.w);
    *(ushort4*)(zhi + (size_t)q * 512 + (t << 2)) = H;
    *(ushort4*)(zlo + (size_t)q * 512 + (t << 2)) = L;
}

// ---------------- workspace layout (float offsets), ~89.4 MB -----------------
#define OFF_KHI 0               /* NKP x 256 bf16 = 12992512 floats */
#define OFF_K2  12992512        /* NKP floats */
#define OFF_QHI 13094016        /* dist bf16 queries 1024x256 = 131072 floats */
#define OFF_Q2  13225088        /* 1024 floats */
#define OFF_QC  13226112        /* qc fp32 1024x256 = 262144 floats */
#define OFF_CP  13488256        /* cand_p 305x1024 uints = 312320 */
#define OFF_I8  13800576        /* 8192 */
#define OFF_W5  13808768        /* 5120 */
#define OFF_I5  13813888        /* 5120 */
#define OFF_WT  13819008        /* transposed split weights, 1441792 floats */
#define OFF_UN  15260800        /* union region, 7077888 floats */

// weight split offsets (floats, relative to OFF_WT): hi then lo per weight
#define W_C1H 0
#define W_C1L 262144
#define W_C2H 524288
#define W_C2L 589824
#define W_C3H 655360
#define W_C3L 688128
#define W_D1H 720896
#define W_D1L 753664
#define W_D2H 786432
#define W_D2L 851968
#define W_D3H 917504
#define W_D3L 1179648

// union region (floats, relative to OFF_UN)
// compress phase:
#define U_H1   0                /* 1024x512 fp32 = 524288 */
#define U_H1H  524288           /* 1024x512 bf16 = 262144 floats */
#define U_H1L  786432
#define U_H2   1048576          /* 1024x256 fp32 = 262144 */
#define U_H2H  1310720          /* 1024x256 bf16 = 131072 floats */
#define U_H2L  1441792
#define U_QSH  1572864          /* query hi 1024x1024 bf16 = 524288 floats */
#define U_QSL  2097152          /* query lo, ends 2621440 */
// decompress phase (reuses same region; qsh/qsl dead after compress gemm #1):
#define U_X0H  0                /* 5120x256 bf16 = 655360 floats */
#define U_X0L  655360
#define U_T1   1310720          /* 5120x256 fp32 = 1310720 */
#define U_T1H  2621440          /* 5120x256 bf16 = 655360 floats */
#define U_T1L  3276800
#define U_T2   3932160          /* 5120x512 fp32 = 2621440 */
#define U_ZH   6553600          /* 1024x512 bf16 = 262144 floats */
#define U_ZL   6815744          /* ends 7077888 */

extern "C" void kernel_launch(void* const* d_in, const int* in_sizes, int n_in,
                              void* d_out, int out_size, void* d_ws, size_t ws_size,
                              hipStream_t stream) {
    const float* query  = (const float*)d_in[0];
    const float* keys   = (const float*)d_in[1];
    const float* values = (const float*)d_in[2];
    const float* cW1 = (const float*)d_in[3];  const float* cb1 = (const float*)d_in[4];
    const float* cg1 = (const float*)d_in[5];  const float* cB1 = (const float*)d_in[6];
    const float* cW2 = (const float*)d_in[7];  const float* cb2 = (const float*)d_in[8];
    const float* cg2 = (const float*)d_in[9];  const float* cB2 = (const float*)d_in[10];
    const float* cW3 = (const float*)d_in[11]; const float* cb3 = (const float*)d_in[12];
    const float* dW1 = (const float*)d_in[13]; const float* db1 = (const float*)d_in[14];
    const float* dg1 = (const float*)d_in[15]; const float* dB1 = (const float*)d_in[16];
    const float* dW2 = (const float*)d_in[17]; const float* db2 = (const float*)d_in[18];
    const float* dg2 = (const float*)d_in[19]; const float* dB2 = (const float*)d_in[20];
    const float* dW3 = (const float*)d_in[21]; const float* db3 = (const float*)d_in[22];
    float* out = (float*)d_out;
    float* ws  = (float*)d_ws;

    unsigned short* khi = (unsigned short*)(ws + OFF_KHI);
    float* k2 = ws + OFF_K2;
    unsigned short* qhi = (unsigned short*)(ws + OFF_QHI);
    float* q2 = ws + OFF_Q2;
    float* qc = ws + OFF_QC;
    unsigned* cand_p = (unsigned*)(ws + OFF_CP);
    int* idx8 = (int*)(ws + OFF_I8);
    float* w5 = ws + OFF_W5;  int* idx5 = (int*)(ws + OFF_I5);
    float* wt = ws + OFF_WT;
    float* un = ws + OFF_UN;

    unsigned short* wc1h = (unsigned short*)(wt + W_C1H);
    unsigned short* wc1l = (unsigned short*)(wt + W_C1L);
    unsigned short* wc2h = (unsigned short*)(wt + W_C2H);
    unsigned short* wc2l = (unsigned short*)(wt + W_C2L);
    unsigned short* wc3h = (unsigned short*)(wt + W_C3H);
    unsigned short* wc3l = (unsigned short*)(wt + W_C3L);
    unsigned short* wd1h = (unsigned short*)(wt + W_D1H);
    unsigned short* wd1l = (unsigned short*)(wt + W_D1L);
    unsigned short* wd2h = (unsigned short*)(wt + W_D2H);
    unsigned short* wd2l = (unsigned short*)(wt + W_D2L);
    unsigned short* wd3h = (unsigned short*)(wt + W_D3H);
    unsigned short* wd3l = (unsigned short*)(wt + W_D3L);

    float* h1 = un + U_H1;
    unsigned short* h1h = (unsigned short*)(un + U_H1H);
    unsigned short* h1l = (unsigned short*)(un + U_H1L);
    float* h2 = un + U_H2;
    unsigned short* h2h = (unsigned short*)(un + U_H2H);
    unsigned short* h2l = (unsigned short*)(un + U_H2L);
    unsigned short* qsh = (unsigned short*)(un + U_QSH);
    unsigned short* qsl = (unsigned short*)(un + U_QSL);
    unsigned short* x0h = (unsigned short*)(un + U_X0H);
    unsigned short* x0l = (unsigned short*)(un + U_X0L);
    float* t1 = un + U_T1;
    unsigned short* t1h = (unsigned short*)(un + U_T1H);
    unsigned short* t1l = (unsigned short*)(un + U_T1L);
    float* t2 = un + U_T2;
    unsigned short* zh = (unsigned short*)(un + U_ZH);
    unsigned short* zl = (unsigned short*)(un + U_ZL);

    // keys -> bf16 + exact k2 (pad rows zeroed)
    prep_rows<<<NKP / 4, 256, 0, stream>>>(keys, khi, k2, NKEYS, NKP);

    // one-time per launch: transpose+split weights, split query
    wsplit<<<dim3(8, 16),  256, 0, stream>>>(cW1, wc1h, wc1l, 1024, 512);
    wsplit<<<dim3(4, 8),   256, 0, stream>>>(cW2, wc2h, wc2l, 512, 256);
    wsplit<<<dim3(4, 4),   256, 0, stream>>>(cW3, wc3h, wc3l, 256, 256);
    wsplit<<<dim3(4, 4),   256, 0, stream>>>(dW1, wd1h, wd1l, 256, 256);
    wsplit<<<dim3(8, 4),   256, 0, stream>>>(dW2, wd2h, wd2l, 256, 512);
    wsplit<<<dim3(16, 8),  256, 0, stream>>>(dW3, wd3h, wd3l, 512, 1024);
    csplit<<<1024, 256, 0, stream>>>(query, qsh, qsl);

    // compress: q_c = MLP(query) via split-bf16 MFMA
    mfma_gemm<<<dim3(8, 16),  256, 0, stream>>>(qsh, qsl, wc1h, wc1l, cb1, h1, 1024, 512, 1024, 1);
    ln_split<<<1024, 256, 0, stream>>>(h1, cg1, cB1, 512, h1h, h1l);
    mfma_gemm<<<dim3(4, 16),  256, 0, stream>>>(h1h, h1l, wc2h, wc2l, cb2, h2, 1024, 256, 512, 1);
    ln_split<<<1024, 256, 0, stream>>>(h2, cg2, cB2, 256, h2h, h2l);
    mfma_gemm<<<dim3(4, 16),  256, 0, stream>>>(h2h, h2l, wc3h, wc3l, cb3, qc, 1024, 256, 256, 0);
    prep_rows<<<256, 256, 0, stream>>>(qc, qhi, q2, 1024, 1024);

    // approx distances via MFMA + fused top-5, then exact rerank of top-8
    dist_topk_mfma<<<SPLITS * 8, 256, 0, stream>>>(khi, qhi, k2, cand_p);
    merge8<<<16, 64, 0, stream>>>(cand_p, idx8);
    rerank<<<256, 256, 0, stream>>>(qc, keys, k2, q2, idx8, w5, idx5, out + 1024 * 1024);

    // decompress 5120 gathered rows via split-bf16 MFMA, combine, final linear
    gather_split<<<5120, 256, 0, stream>>>(values, idx5, x0h, x0l);
    mfma_gemm<<<dim3(4, 80),  256, 0, stream>>>(x0h, x0l, wd1h, wd1l, db1, t1, 5120, 256, 256, 1);
    ln_split<<<5120, 256, 0, stream>>>(t1, dg1, dB1, 256, t1h, t1l);
    mfma_gemm<<<dim3(8, 80),  256, 0, stream>>>(t1h, t1l, wd2h, wd2l, db2, t2, 5120, 512, 256, 1);
    ln_rows<<<5120, 256, 0, stream>>>(t2, dg2, dB2, 512);
    combine_split<<<1024, 128, 0, stream>>>(t2, w5, zh, zl);
    mfma_gemm<<<dim3(16, 16), 256, 0, stream>>>(zh, zl, wd3h, wd3l, db3, out, 1024, 1024, 512, 0);
}

// Round 5
// 495.547 us; speedup vs baseline: 1.8284x; 1.1240x over previous
//
#include <hip/hip_runtime.h>
#include <cfloat>
#include <cstddef>

typedef __attribute__((ext_vector_type(8))) short bf16x8;
typedef __attribute__((ext_vector_type(4))) float f32x4;

#define NKEYS    100000
#define SPLITS   61
#define SPLITLEN 1664
#define NKP      (SPLITS * SPLITLEN)   /* 101504 padded key rows */
#define NCHUNK   (SPLITLEN / 128)      /* 13 chunks of 128 keys */
#define PREPB    (NKP / 4)             /* 25376 key-prep blocks */
#define CSPLB    1024                  /* query-split blocks */
#define WSPB     352                   /* weight-split tile blocks */

// ---------------- helpers ----------------------------------------------------
__device__ __forceinline__ unsigned short f2bf(float x) {
    unsigned int u = __float_as_uint(x);
    unsigned int r = (u + 0x7fffu + ((u >> 16) & 1u)) >> 16;
    return (unsigned short)r;
}
__device__ __forceinline__ float bf2f(unsigned short h) {
    return __uint_as_float((unsigned)h << 16);
}
// fp32 -> bf16 hi + bf16 lo (x ~= hi + lo to ~2^-17 rel)
__device__ __forceinline__ void split2(float x, unsigned short& h, unsigned short& l) {
    h = f2bf(x);
    float r = x - bf2f(h);
    l = f2bf(r);
}

__device__ __forceinline__ void async16(void* lds, const void* g) {
    __builtin_amdgcn_global_load_lds(
        (const __attribute__((address_space(1))) unsigned int*)g,
        (__attribute__((address_space(3))) unsigned int*)lds, 16, 0, 0);
}

// monotone float->uint (3 ops), keep 21 high bits, pack 11-bit local key index
__device__ __forceinline__ unsigned pack_si(float sc, unsigned local) {
    unsigned u = __float_as_uint(sc);
    unsigned m = u ^ ((unsigned)((int)u >> 31) | 0x80000000u);
    return (m & 0xFFFFF800u) | local;
}

// branchless descending-sorted insert: one min/max pass (2 VALU/level).
// If v <= a[4] the array is provably unchanged, so running it is always safe.
__device__ __forceinline__ void chain5(unsigned (&a)[5], unsigned v) {
    #pragma unroll
    for (int i = 0; i < 5; ++i) {
        unsigned t = min(a[i], v);
        a[i] = max(a[i], v);
        v = t;
    }
}
// wave-ballot guard: v_cmp + scalar branch in the common (no-insert) case
__device__ __forceinline__ void ins5u(unsigned (&a)[5], unsigned v) {
    if (__any((int)(v > a[4]))) chain5(a, v);
}

// guarded sorted insert of (score,idx) pair into descending top-8
__device__ __forceinline__ void ins8p(unsigned (&s)[8], int (&ix)[8], unsigned v, int vi) {
    if (v > s[7]) {
        s[7] = v; ix[7] = vi;
        #pragma unroll
        for (int i = 7; i > 0; --i) {
            if (s[i] > s[i - 1]) {
                unsigned tv = s[i]; s[i] = s[i - 1]; s[i - 1] = tv;
                int ti = ix[i]; ix[i] = ix[i - 1]; ix[i - 1] = ti;
            }
        }
    }
}

// ---------------- split-bf16 MFMA GEMM: C = act(A@W + bias) ------------------
// A hi/lo bf16 [M][K]; W transposed+split hi/lo bf16 [N][K].
// acc = Ahi*Whi + Ahi*Wlo + Alo*Whi (3 MFMA passes, ~2^-17 rel error).
// Block: 64x64 tile, 4 waves (2x2), each wave 32x32 = 2x2 16x16 frags.
__global__ __launch_bounds__(256, 2) void mfma_gemm(
    const unsigned short* __restrict__ Ahi, const unsigned short* __restrict__ Alo,
    const unsigned short* __restrict__ Whi, const unsigned short* __restrict__ Wlo,
    const float* __restrict__ bias, float* __restrict__ C,
    int M, int N, int K, int do_gelu)
{
    __shared__ unsigned short sT[2][8192];   // 2 x 16 KB (4 arrays x 4 tiles x 1KB)
    const int tid = threadIdx.x;
    const int lane = tid & 63;
    const int wv = tid >> 6;
    const int wr = wv >> 1, wc = wv & 1;
    const int m0 = blockIdx.y << 6, n0 = blockIdx.x << 6;

    const int rl = lane & 15, kq = (lane >> 4) << 3;
    const unsigned short* sp[4];
    sp[0] = Ahi + (size_t)(m0 + (wv << 4) + rl) * K + kq;
    sp[1] = Alo + (size_t)(m0 + (wv << 4) + rl) * K + kq;
    sp[2] = Whi + (size_t)(n0 + (wv << 4) + rl) * K + kq;
    sp[3] = Wlo + (size_t)(n0 + (wv << 4) + rl) * K + kq;
    const int ldss = (wv << 9) | (lane << 3);

    f32x4 acc[2][2];
    #pragma unroll
    for (int p = 0; p < 2; ++p)
        #pragma unroll
        for (int q = 0; q < 2; ++q) acc[p][q] = (f32x4){0.f, 0.f, 0.f, 0.f};

    const int steps = K >> 5;
    #pragma unroll
    for (int i = 0; i < 4; ++i)
        async16(&sT[0][(i << 11) + ldss], sp[i]);

    for (int s = 0; s < steps; ++s) {
        const int cur = s & 1;
        __syncthreads();                       // buf[cur] staged (vmcnt drained)
        if (s + 1 < steps) {
            const int ko = (s + 1) << 5;
            #pragma unroll
            for (int i = 0; i < 4; ++i)
                async16(&sT[cur ^ 1][(i << 11) + ldss], sp[i] + ko);
        }
        bf16x8 ah[2], al[2], wh[2], wl[2];
        #pragma unroll
        for (int p = 0; p < 2; ++p) {
            ah[p] = *(const bf16x8*)&sT[cur][(((wr << 1) + p) << 9) | (lane << 3)];
            al[p] = *(const bf16x8*)&sT[cur][2048 + ((((wr << 1) + p) << 9) | (lane << 3))];
        }
        #pragma unroll
        for (int q = 0; q < 2; ++q) {
            wh[q] = *(const bf16x8*)&sT[cur][4096 + ((((wc << 1) + q) << 9) | (lane << 3))];
            wl[q] = *(const bf16x8*)&sT[cur][6144 + ((((wc << 1) + q) << 9) | (lane << 3))];
        }
        #pragma unroll
        for (int p = 0; p < 2; ++p)
            #pragma unroll
            for (int q = 0; q < 2; ++q) {
                acc[p][q] = __builtin_amdgcn_mfma_f32_16x16x32_bf16(ah[p], wh[q], acc[p][q], 0, 0, 0);
                acc[p][q] = __builtin_amdgcn_mfma_f32_16x16x32_bf16(ah[p], wl[q], acc[p][q], 0, 0, 0);
                acc[p][q] = __builtin_amdgcn_mfma_f32_16x16x32_bf16(al[p], wh[q], acc[p][q], 0, 0, 0);
            }
    }

    #pragma unroll
    for (int q = 0; q < 2; ++q) {
        const int n = n0 + (((wc << 1) + q) << 4) + (lane & 15);
        const float bn = bias[n];
        #pragma unroll
        for (int p = 0; p < 2; ++p) {
            #pragma unroll
            for (int j = 0; j < 4; ++j) {
                const int m = m0 + (((wr << 1) + p) << 4) + ((lane >> 4) << 2) + j;
                float v = acc[p][q][j] + bn;
                if (do_gelu) v = 0.5f * v * (1.0f + erff(v * 0.70710678118654752f));
                C[(size_t)m * N + n] = v;
            }
        }
    }
}

// ---------------- device: weight transpose+split tile ------------------------
__device__ __forceinline__ void wsplit_tile(
    const float* __restrict__ W, unsigned short* __restrict__ Thi,
    unsigned short* __restrict__ Tlo, int K, int N, int n0, int k0, int tid)
{
    __shared__ float tile[64][65];
    const int nl = tid & 63, kg = tid >> 6;
    #pragma unroll
    for (int r = 0; r < 16; ++r)
        tile[kg + (r << 2)][nl] = W[(size_t)(k0 + kg + (r << 2)) * N + n0 + nl];
    __syncthreads();
    const int nn = tid >> 2, kc = (tid & 3) << 4;
    unsigned short* ph = Thi + (size_t)(n0 + nn) * K + k0 + kc;
    unsigned short* pl = Tlo + (size_t)(n0 + nn) * K + k0 + kc;
    #pragma unroll
    for (int c = 0; c < 16; c += 4) {
        ushort4 H, L;
        split2(tile[kc + c + 0][nn], H.x, L.x);
        split2(tile[kc + c + 1][nn], H.y, L.y);
        split2(tile[kc + c + 2][nn], H.z, L.z);
        split2(tile[kc + c + 3][nn], H.w, L.w);
        *(ushort4*)(ph + c) = H;
        *(ushort4*)(pl + c) = L;
    }
}

// ---------------- device: fp32 row group -> bf16 + squared norm --------------
// pad rows (row >= nvalid): khi = 0, k2 = FLT_MAX -> score -1.7e38, self-excluding
__device__ __forceinline__ void prep_group(
    const float* __restrict__ X, unsigned short* __restrict__ xh,
    float* __restrict__ x2, int nvalid, int grp, int tid)
{
    const int row = (grp << 2) + (tid >> 6);
    const int lane = tid & 63;
    if (row < nvalid) {
        float4 v = *(const float4*)(X + ((size_t)row << 8) + (lane << 2));
        float ss = v.x * v.x + v.y * v.y + v.z * v.z + v.w * v.w;
        #pragma unroll
        for (int off = 32; off > 0; off >>= 1) ss += __shfl_xor(ss, off);
        ushort4 h;
        h.x = f2bf(v.x); h.y = f2bf(v.y); h.z = f2bf(v.z); h.w = f2bf(v.w);
        *(ushort4*)(xh + ((size_t)row << 8) + (lane << 2)) = h;
        if (lane == 0) x2[row] = ss;
    } else {
        ushort4 z = {0, 0, 0, 0};
        *(ushort4*)(xh + ((size_t)row << 8) + (lane << 2)) = z;
        if (lane == 0) x2[row] = FLT_MAX;
    }
}

// ---------------- kernel: all input prep (keys, query split, weight split) ---
__global__ __launch_bounds__(256) void prep_all(
    const float* __restrict__ keys, unsigned short* __restrict__ khi, float* __restrict__ k2,
    const float* __restrict__ query, unsigned short* __restrict__ qsh, unsigned short* __restrict__ qsl,
    const float* __restrict__ cW1, const float* __restrict__ cW2, const float* __restrict__ cW3,
    const float* __restrict__ dW1, const float* __restrict__ dW2, const float* __restrict__ dW3,
    unsigned short* wc1h, unsigned short* wc1l, unsigned short* wc2h, unsigned short* wc2l,
    unsigned short* wc3h, unsigned short* wc3l, unsigned short* wd1h, unsigned short* wd1l,
    unsigned short* wd2h, unsigned short* wd2l, unsigned short* wd3h, unsigned short* wd3l)
{
    const int bid = blockIdx.x;
    const int tid = threadIdx.x;
    if (bid < PREPB) {                         // keys -> bf16 + k2
        prep_group(keys, khi, k2, NKEYS, bid, tid);
        return;
    }
    if (bid < PREPB + CSPLB) {                 // query -> hi/lo split
        const size_t i = ((size_t)(bid - PREPB) * 256 + tid) << 2;
        float4 v = *(const float4*)(query + i);
        ushort4 H, L;
        split2(v.x, H.x, L.x);
        split2(v.y, H.y, L.y);
        split2(v.z, H.z, L.z);
        split2(v.w, H.w, L.w);
        *(ushort4*)(qsh + i) = H;
        *(ushort4*)(qsl + i) = L;
        return;
    }
    int t = bid - (PREPB + CSPLB);             // weight transpose+split tiles
    const float* W; unsigned short *Th, *Tl; int K, N;
    if (t < 128)      {          W = cW1; Th = wc1h; Tl = wc1l; K = 1024; N = 512;  }
    else if (t < 160) { t -= 128; W = cW2; Th = wc2h; Tl = wc2l; K = 512;  N = 256;  }
    else if (t < 176) { t -= 160; W = cW3; Th = wc3h; Tl = wc3l; K = 256;  N = 256;  }
    else if (t < 192) { t -= 176; W = dW1; Th = wd1h; Tl = wd1l; K = 256;  N = 256;  }
    else if (t < 224) { t -= 192; W = dW2; Th = wd2h; Tl = wd2l; K = 256;  N = 512;  }
    else              { t -= 224; W = dW3; Th = wd3h; Tl = wd3l; K = 512;  N = 1024; }
    const int nx = N >> 6;
    wsplit_tile(W, Th, Tl, K, N, (t % nx) << 6, (t / nx) << 6, tid);
}

// ---------------- kernel: qc -> bf16 + squared norms -------------------------
__global__ __launch_bounds__(256) void prep_q(
    const float* __restrict__ X, unsigned short* __restrict__ xh, float* __restrict__ x2)
{
    prep_group(X, xh, x2, 1024, blockIdx.x, threadIdx.x);
}

// ---------------- row LayerNorm (in-place fp32), C in {256,512} --------------
__global__ __launch_bounds__(256) void ln_rows(
    float* __restrict__ X, const float* __restrict__ g, const float* __restrict__ b, int C)
{
    const int row = blockIdx.x;
    const int tid = threadIdx.x;
    float* xr = X + (size_t)row * C;
    float v0 = xr[tid];
    float v1 = (C > 256) ? xr[tid + 256] : 0.0f;
    float s = v0 + v1;
    float ss = v0 * v0 + v1 * v1;
    #pragma unroll
    for (int off = 32; off > 0; off >>= 1) {
        s  += __shfl_xor(s, off);
        ss += __shfl_xor(ss, off);
    }
    __shared__ float red[10];
    const int wave = tid >> 6, lane = tid & 63;
    if (lane == 0) { red[wave] = s; red[wave + 4] = ss; }
    __syncthreads();
    if (tid == 0) {
        float S  = red[0] + red[1] + red[2] + red[3];
        float SS = red[4] + red[5] + red[6] + red[7];
        float m = S / C;
        float var = SS / C - m * m;
        red[8] = m;
        red[9] = 1.0f / sqrtf(var + 1e-5f);
    }
    __syncthreads();
    float m = red[8], inv = red[9];
    xr[tid] = (v0 - m) * inv * g[tid] + b[tid];
    if (C > 256) xr[tid + 256] = (v1 - m) * inv * g[tid + 256] + b[tid + 256];
}

// ---------------- row LayerNorm -> bf16 hi/lo outputs ------------------------
__global__ __launch_bounds__(256) void ln_split(
    const float* __restrict__ X, const float* __restrict__ g, const float* __restrict__ b,
    int C, unsigned short* __restrict__ hi, unsigned short* __restrict__ lo)
{
    const int row = blockIdx.x;
    const int tid = threadIdx.x;
    const float* xr = X + (size_t)row * C;
    float v0 = xr[tid];
    float v1 = (C > 256) ? xr[tid + 256] : 0.0f;
    float s = v0 + v1;
    float ss = v0 * v0 + v1 * v1;
    #pragma unroll
    for (int off = 32; off > 0; off >>= 1) {
        s  += __shfl_xor(s, off);
        ss += __shfl_xor(ss, off);
    }
    __shared__ float red[10];
    const int wave = tid >> 6, lane = tid & 63;
    if (lane == 0) { red[wave] = s; red[wave + 4] = ss; }
    __syncthreads();
    if (tid == 0) {
        float S  = red[0] + red[1] + red[2] + red[3];
        float SS = red[4] + red[5] + red[6] + red[7];
        float m = S / C;
        float var = SS / C - m * m;
        red[8] = m;
        red[9] = 1.0f / sqrtf(var + 1e-5f);
    }
    __syncthreads();
    float m = red[8], inv = red[9];
    {
        float y = (v0 - m) * inv * g[tid] + b[tid];
        unsigned short h, l; split2(y, h, l);
        hi[(size_t)row * C + tid] = h;
        lo[(size_t)row * C + tid] = l;
    }
    if (C > 256) {
        float y = (v1 - m) * inv * g[tid + 256] + b[tid + 256];
        unsigned short h, l; split2(y, h, l);
        hi[(size_t)row * C + tid + 256] = h;
        lo[(size_t)row * C + tid + 256] = l;
    }
}

// ---------------- MFMA distance + fused per-split top-5 ----------------------
__global__ __launch_bounds__(256, 2) void dist_topk_mfma(
    const unsigned short* __restrict__ khi, const unsigned short* __restrict__ qhi,
    const float* __restrict__ k2, unsigned* __restrict__ cand_p)
{
    __shared__ unsigned short sB[2][8192];   // 2 x 16 KB double buffer
    const int tid = threadIdx.x;
    const int lane = tid & 63;
    const int wv = tid >> 6;

    const int fid = blockIdx.x;
    const int rr = fid & 7, row = fid >> 3;            // row in 0..60
    int split, jq;
    if (row < 56) { split = rr * 7 + (row >> 3); jq = row & 7; }
    else { int slot = ((row - 56) << 3) + rr; split = 56 + (slot >> 3); jq = slot & 7; }
    const int kstart = split * SPLITLEN;
    const int q0 = jq * 128 + wv * 32;

    bf16x8 aF[2][8];
    #pragma unroll
    for (int qt = 0; qt < 2; ++qt) {
        const unsigned short* qb = qhi
            + (((size_t)(q0 + qt * 16 + (lane & 15))) << 8) + ((lane >> 4) << 3);
        #pragma unroll
        for (int s = 0; s < 8; ++s) aF[qt][s] = *(const bf16x8*)(qb + s * 32);
    }

    size_t soff[4];
    int ldst[4];
    #pragma unroll
    for (int i = 0; i < 4; ++i) {
        int e = i * 256 + tid;
        int h = e >> 9, t = (e >> 6) & 7, L = e & 63;
        soff[i] = (((size_t)(kstart + t * 16 + (L & 15))) << 8)
                + (h << 5) + ((L >> 4) << 3);
        ldst[i] = e << 3;
    }

    unsigned bp[2][4][5];
    #pragma unroll
    for (int qt = 0; qt < 2; ++qt)
        #pragma unroll
        for (int r = 0; r < 4; ++r)
            #pragma unroll
            for (int j = 0; j < 5; ++j) bp[qt][r][j] = 0u;

    #pragma unroll
    for (int i = 0; i < 4; ++i)
        async16(&sB[0][ldst[i]], khi + soff[i]);

    int cur = 0;
    for (int c = 0; c < NCHUNK; ++c) {
        const int coff = c << 15;
        f32x4 acc[2][8];
        #pragma unroll
        for (int qt = 0; qt < 2; ++qt)
            #pragma unroll
            for (int t = 0; t < 8; ++t) acc[qt][t] = (f32x4){0.f, 0.f, 0.f, 0.f};

        #pragma unroll
        for (int st = 0; st < 4; ++st) {
            __syncthreads();
            const int g = (c << 2) + st;
            if (g + 1 < NCHUNK * 4) {
                const int ns = (st + 1) & 3;
                const int ncoff = (st == 3) ? (coff + 32768) : coff;
                #pragma unroll
                for (int i = 0; i < 4; ++i)
                    async16(&sB[cur ^ 1][ldst[i]],
                            khi + soff[i] + (size_t)(ncoff + (ns << 6)));
            }
            #pragma unroll
            for (int h = 0; h < 2; ++h) {
                #pragma unroll
                for (int t = 0; t < 8; ++t) {
                    bf16x8 b = *(const bf16x8*)
                        &sB[cur][((((h << 3) + t) << 6) | lane) << 3];
                    acc[0][t] = __builtin_amdgcn_mfma_f32_16x16x32_bf16(
                        aF[0][(st << 1) + h], b, acc[0][t], 0, 0, 0);
                    acc[1][t] = __builtin_amdgcn_mfma_f32_16x16x32_bf16(
                        aF[1][(st << 1) + h], b, acc[1][t], 0, 0, 0);
                }
            }
            cur ^= 1;
        }

        const int kb = c << 7;
        #pragma unroll
        for (int t = 0; t < 8; ++t) {
            const unsigned local = (unsigned)(kb + t * 16 + (lane & 15));
            const float k2v = k2[kstart + (int)local];   // pads hold FLT_MAX
            #pragma unroll
            for (int qt = 0; qt < 2; ++qt)
                #pragma unroll
                for (int r = 0; r < 4; ++r) {
                    float sc = fmaf(-0.5f, k2v, acc[qt][t][r]);
                    ins5u(bp[qt][r], pack_si(sc, local));
                }
        }
    }

    #pragma unroll
    for (int m = 1; m <= 8; m <<= 1) {
        #pragma unroll
        for (int qt = 0; qt < 2; ++qt)
            #pragma unroll
            for (int r = 0; r < 4; ++r) {
                unsigned o[5];
                #pragma unroll
                for (int j = 0; j < 5; ++j)
                    o[j] = (unsigned)__shfl_xor((int)bp[qt][r][j], m);
                #pragma unroll
                for (int j = 0; j < 5; ++j) ins5u(bp[qt][r], o[j]);
            }
    }
    if ((lane & 15) == 0) {
        #pragma unroll
        for (int qt = 0; qt < 2; ++qt)
            #pragma unroll
            for (int r = 0; r < 4; ++r) {
                const int q = q0 + qt * 16 + ((lane >> 4) << 2) + r;
                #pragma unroll
                for (int j = 0; j < 5; ++j)
                    cand_p[(size_t)(split * 5 + j) * 1024 + q] = bp[qt][r][j];
            }
    }
}

// ---------------- fused merge + exact rerank + gather ------------------------
// One wave per query: lane-strided scan of 305 candidates -> 64-lane butterfly
// top-8 -> exact fp32 rerank (indices already in registers) -> w5/conf ->
// gather + split the 5 selected value rows.
__global__ __launch_bounds__(256) void mrg_rank_gather(
    const unsigned* __restrict__ cand_p,
    const float* __restrict__ qc, const float* __restrict__ keys,
    const float* __restrict__ k2, const float* __restrict__ q2,
    float* __restrict__ w5, float* __restrict__ conf,
    const float* __restrict__ values,
    unsigned short* __restrict__ x0h, unsigned short* __restrict__ x0l)
{
    const int tid = threadIdx.x;
    const int lane = tid & 63;
    const int q = (blockIdx.x << 2) + (tid >> 6);

    // Phase A: per-lane partial top-8 over the 305 packed candidates
    unsigned fp[8]; int fi[8];
    #pragma unroll
    for (int j = 0; j < 8; ++j) { fp[j] = 0u; fi[j] = 0; }
    for (int t = lane; t < SPLITS * 5; t += 64) {
        unsigned v = cand_p[(size_t)t * 1024 + q];
        ins8p(fp, fi, v, (t / 5) * SPLITLEN + (int)(v & 2047u));
    }
    // butterfly merge across all 64 lanes -> every lane holds global top-8
    #pragma unroll
    for (int m = 1; m <= 32; m <<= 1) {
        unsigned op[8]; int oi[8];
        #pragma unroll
        for (int j = 0; j < 8; ++j) {
            op[j] = (unsigned)__shfl_xor((int)fp[j], m);
            oi[j] = __shfl_xor(fi[j], m);
        }
        #pragma unroll
        for (int j = 0; j < 8; ++j) ins8p(fp, fi, op[j], oi[j]);
    }

    // Phase B: exact fp32 rerank of the 8 candidates (wave-parallel dots)
    const float4 qv = *(const float4*)(qc + ((size_t)q << 8) + (lane << 2));
    float dot[8];
    #pragma unroll
    for (int c = 0; c < 8; ++c) {
        const float4 kv = *(const float4*)(keys + ((size_t)fi[c] << 8) + (lane << 2));
        dot[c] = qv.x * kv.x + qv.y * kv.y + qv.z * kv.z + qv.w * kv.w;
    }
    #pragma unroll
    for (int c = 0; c < 8; ++c)
        #pragma unroll
        for (int off = 32; off > 0; off >>= 1) dot[c] += __shfl_xor(dot[c], off);
    // all lanes hold identical sums -> compute and sort redundantly (uniform)
    float d[8]; int di[8];
    const float qq = q2[q];
    #pragma unroll
    for (int c = 0; c < 8; ++c) {
        d[c] = fmaxf(qq + k2[fi[c]] - 2.0f * dot[c], 0.0f);
        di[c] = fi[c];
    }
    #pragma unroll
    for (int a = 1; a < 8; ++a) {               // insertion sort ascending
        float dv = d[a]; int iv = di[a]; int b = a;
        while (b > 0 && d[b - 1] > dv) { d[b] = d[b - 1]; di[b] = di[b - 1]; --b; }
        d[b] = dv; di[b] = iv;
    }
    float w[5], sum = 0.0f;
    #pragma unroll
    for (int j = 0; j < 5; ++j) { w[j] = 1.0f / (d[j] + 1e-6f); sum += w[j]; }
    if (lane == 0) {
        #pragma unroll
        for (int j = 0; j < 5; ++j) w5[q * 5 + j] = w[j] / sum;
        conf[q] = 1.0f / (d[0] + 1e-6f);
    }

    // Phase C: gather + hi/lo split the 5 selected value rows
    #pragma unroll
    for (int j = 0; j < 5; ++j) {
        const size_t r = (size_t)q * 5 + j;
        const float4 v = *(const float4*)(values + ((size_t)di[j] << 8) + (lane << 2));
        ushort4 H, L;
        split2(v.x, H.x, L.x);
        split2(v.y, H.y, L.y);
        split2(v.z, H.z, L.z);
        split2(v.w, H.w, L.w);
        *(ushort4*)(x0h + (r << 8) + (lane << 2)) = H;
        *(ushort4*)(x0l + (r << 8) + (lane << 2)) = L;
    }
}

// ---------------- weighted combine of 5 rows -> bf16 hi/lo z -----------------
__global__ __launch_bounds__(128) void combine_split(
    const float* __restrict__ h2d, const float* __restrict__ w5,
    unsigned short* __restrict__ zhi, unsigned short* __restrict__ zlo)
{
    const int q = blockIdx.x;
    const int t = threadIdx.x;
    float4 acc = {0.0f, 0.0f, 0.0f, 0.0f};
    #pragma unroll
    for (int i = 0; i < 5; ++i) {
        float w = w5[q * 5 + i];
        float4 v = *(const float4*)(h2d + ((size_t)q * 5 + i) * 512 + (t << 2));
        acc.x = fmaf(w, v.x, acc.x);
        acc.y = fmaf(w, v.y, acc.y);
        acc.z = fmaf(w, v.z, acc.z);
        acc.w = fmaf(w, v.w, acc.w);
    }
    ushort4 H, L;
    split2(acc.x, H.x, L.x);
    split2(acc.y, H.y, L.y);
    split2(acc.z, H.z, L.z);
    split2(acc.w, H.w, L.w);
    *(ushort4*)(zhi + (size_t)q * 512 + (t << 2)) = H;
    *(ushort4*)(zlo + (size_t)q * 512 + (t << 2)) = L;
}

// ---------------- workspace layout (float offsets), ~89.4 MB -----------------
#define OFF_KHI 0
#define OFF_K2  12992512
#define OFF_QHI 13094016
#define OFF_Q2  13225088
#define OFF_QC  13226112
#define OFF_CP  13488256
#define OFF_W5  13808768
#define OFF_WT  13819008
#define OFF_UN  15260800

#define W_C1H 0
#define W_C1L 262144
#define W_C2H 524288
#define W_C2L 589824
#define W_C3H 655360
#define W_C3L 688128
#define W_D1H 720896
#define W_D1L 753664
#define W_D2H 786432
#define W_D2L 851968
#define W_D3H 917504
#define W_D3L 1179648

#define U_H1   0
#define U_H1H  524288
#define U_H1L  786432
#define U_H2   1048576
#define U_H2H  1310720
#define U_H2L  1441792
#define U_QSH  1572864
#define U_QSL  2097152
#define U_X0H  0
#define U_X0L  655360
#define U_T1   1310720
#define U_T1H  2621440
#define U_T1L  3276800
#define U_T2   3932160
#define U_ZH   6553600
#define U_ZL   6815744

extern "C" void kernel_launch(void* const* d_in, const int* in_sizes, int n_in,
                              void* d_out, int out_size, void* d_ws, size_t ws_size,
                              hipStream_t stream) {
    const float* query  = (const float*)d_in[0];
    const float* keys   = (const float*)d_in[1];
    const float* values = (const float*)d_in[2];
    const float* cW1 = (const float*)d_in[3];  const float* cb1 = (const float*)d_in[4];
    const float* cg1 = (const float*)d_in[5];  const float* cB1 = (const float*)d_in[6];
    const float* cW2 = (const float*)d_in[7];  const float* cb2 = (const float*)d_in[8];
    const float* cg2 = (const float*)d_in[9];  const float* cB2 = (const float*)d_in[10];
    const float* cW3 = (const float*)d_in[11]; const float* cb3 = (const float*)d_in[12];
    const float* dW1 = (const float*)d_in[13]; const float* db1 = (const float*)d_in[14];
    const float* dg1 = (const float*)d_in[15]; const float* dB1 = (const float*)d_in[16];
    const float* dW2 = (const float*)d_in[17]; const float* db2 = (const float*)d_in[18];
    const float* dg2 = (const float*)d_in[19]; const float* dB2 = (const float*)d_in[20];
    const float* dW3 = (const float*)d_in[21]; const float* db3 = (const float*)d_in[22];
    float* out = (float*)d_out;
    float* ws  = (float*)d_ws;

    unsigned short* khi = (unsigned short*)(ws + OFF_KHI);
    float* k2 = ws + OFF_K2;
    unsigned short* qhi = (unsigned short*)(ws + OFF_QHI);
    float* q2 = ws + OFF_Q2;
    float* qc = ws + OFF_QC;
    unsigned* cand_p = (unsigned*)(ws + OFF_CP);
    float* w5 = ws + OFF_W5;
    float* wt = ws + OFF_WT;
    float* un = ws + OFF_UN;

    unsigned short* wc1h = (unsigned short*)(wt + W_C1H);
    unsigned short* wc1l = (unsigned short*)(wt + W_C1L);
    unsigned short* wc2h = (unsigned short*)(wt + W_C2H);
    unsigned short* wc2l = (unsigned short*)(wt + W_C2L);
    unsigned short* wc3h = (unsigned short*)(wt + W_C3H);
    unsigned short* wc3l = (unsigned short*)(wt + W_C3L);
    unsigned short* wd1h = (unsigned short*)(wt + W_D1H);
    unsigned short* wd1l = (unsigned short*)(wt + W_D1L);
    unsigned short* wd2h = (unsigned short*)(wt + W_D2H);
    unsigned short* wd2l = (unsigned short*)(wt + W_D2L);
    unsigned short* wd3h = (unsigned short*)(wt + W_D3H);
    unsigned short* wd3l = (unsigned short*)(wt + W_D3L);

    float* h1 = un + U_H1;
    unsigned short* h1h = (unsigned short*)(un + U_H1H);
    unsigned short* h1l = (unsigned short*)(un + U_H1L);
    float* h2 = un + U_H2;
    unsigned short* h2h = (unsigned short*)(un + U_H2H);
    unsigned short* h2l = (unsigned short*)(un + U_H2L);
    unsigned short* qsh = (unsigned short*)(un + U_QSH);
    unsigned short* qsl = (unsigned short*)(un + U_QSL);
    unsigned short* x0h = (unsigned short*)(un + U_X0H);
    unsigned short* x0l = (unsigned short*)(un + U_X0L);
    float* t1 = un + U_T1;
    unsigned short* t1h = (unsigned short*)(un + U_T1H);
    unsigned short* t1l = (unsigned short*)(un + U_T1L);
    float* t2 = un + U_T2;
    unsigned short* zh = (unsigned short*)(un + U_ZH);
    unsigned short* zl = (unsigned short*)(un + U_ZL);
    float* conf = out + 1024 * 1024;

    // L1: all independent prep (keys bf16+k2, query split, weight transpose+split)
    prep_all<<<PREPB + CSPLB + WSPB, 256, 0, stream>>>(
        keys, khi, k2, query, qsh, qsl,
        cW1, cW2, cW3, dW1, dW2, dW3,
        wc1h, wc1l, wc2h, wc2l, wc3h, wc3l, wd1h, wd1l, wd2h, wd2l, wd3h, wd3l);

    // compress: q_c = MLP(query) via split-bf16 MFMA
    mfma_gemm<<<dim3(8, 16),  256, 0, stream>>>(qsh, qsl, wc1h, wc1l, cb1, h1, 1024, 512, 1024, 1);
    ln_split<<<1024, 256, 0, stream>>>(h1, cg1, cB1, 512, h1h, h1l);
    mfma_gemm<<<dim3(4, 16),  256, 0, stream>>>(h1h, h1l, wc2h, wc2l, cb2, h2, 1024, 256, 512, 1);
    ln_split<<<1024, 256, 0, stream>>>(h2, cg2, cB2, 256, h2h, h2l);
    mfma_gemm<<<dim3(4, 16),  256, 0, stream>>>(h2h, h2l, wc3h, wc3l, cb3, qc, 1024, 256, 256, 0);
    prep_q<<<256, 256, 0, stream>>>(qc, qhi, q2);

    // approx distances via MFMA + fused top-5; fused merge/rerank/gather
    dist_topk_mfma<<<SPLITS * 8, 256, 0, stream>>>(khi, qhi, k2, cand_p);
    mrg_rank_gather<<<256, 256, 0, stream>>>(cand_p, qc, keys, k2, q2, w5, conf,
                                             values, x0h, x0l);

    // decompress 5120 gathered rows via split-bf16 MFMA, combine, final linear
    mfma_gemm<<<dim3(4, 80),  256, 0, stream>>>(x0h, x0l, wd1h, wd1l, db1, t1, 5120, 256, 256, 1);
    ln_split<<<5120, 256, 0, stream>>>(t1, dg1, dB1, 256, t1h, t1l);
    mfma_gemm<<<dim3(8, 80),  256, 0, stream>>>(t1h, t1l, wd2h, wd2l, db2, t2, 5120, 512, 256, 1);
    ln_rows<<<5120, 256, 0, stream>>>(t2, dg2, dB2, 512);
    combine_split<<<1024, 128, 0, stream>>>(t2, w5, zh, zl);
    mfma_gemm<<<dim3(16, 16), 256, 0, stream>>>(zh, zl, wd3h, wd3l, db3, out, 1024, 1024, 512, 0);
}